// Round 1
// baseline (41.840 us; speedup 1.0000x reference)
//
#include <hip/hip_runtime.h>

#define BINS 16
#define OUT_DIM 64
#define NB 64
#define NCH 3
#define NPIX (512 * 512)           // pixels per (b,c) plane
#define THREADS 256
#define BLOCKS_PER_PLANE 16
#define CHUNK_PIX (NPIX / BLOCKS_PER_PLANE)        // 16384 pixels per block
#define VEC_ITERS (CHUNK_PIX / 4 / THREADS)        // 16 float4 per thread

// Kernel 1: per-(b,c)-plane 16-bin histogram.
// LDS histogram replicated 64x (one copy per lane): addr = bin*64 + lane.
// bank = lane%32 -> 2-way lane aliasing only (free), zero same-address contention.
__global__ __launch_bounds__(THREADS) void hist_kernel(const float* __restrict__ x,
                                                       unsigned int* __restrict__ ghist) {
    __shared__ unsigned int lh[BINS * 64];
    for (int i = threadIdx.x; i < BINS * 64; i += THREADS) lh[i] = 0u;
    __syncthreads();

    const int plane = blockIdx.x / BLOCKS_PER_PLANE;   // b*3 + c
    const int chunk = blockIdx.x % BLOCKS_PER_PLANE;
    const int lane  = threadIdx.x & 63;

    const float4* __restrict__ src =
        (const float4*)(x + (size_t)plane * NPIX + (size_t)chunk * CHUNK_PIX);

    #pragma unroll
    for (int it = 0; it < VEC_ITERS; ++it) {
        float4 v = src[it * THREADS + threadIdx.x];
        // x in [0,1): (int)(x*16.0f) == floor(x*16) exactly (mul by 2^4 is exact)
        int i0 = min(BINS - 1, max(0, (int)(v.x * 16.0f)));
        int i1 = min(BINS - 1, max(0, (int)(v.y * 16.0f)));
        int i2 = min(BINS - 1, max(0, (int)(v.z * 16.0f)));
        int i3 = min(BINS - 1, max(0, (int)(v.w * 16.0f)));
        atomicAdd(&lh[i0 * 64 + lane], 1u);
        atomicAdd(&lh[i1 * 64 + lane], 1u);
        atomicAdd(&lh[i2 * 64 + lane], 1u);
        atomicAdd(&lh[i3 * 64 + lane], 1u);
    }
    __syncthreads();

    if (threadIdx.x < BINS) {
        unsigned int s = 0;
        #pragma unroll
        for (int k = 0; k < 64; ++k) s += lh[threadIdx.x * 64 + k];
        atomicAdd(&ghist[plane * BINS + threadIdx.x], s);
    }
}

// Kernel 2: out[b][o] = relu( sum_k (ghist[b*48+k]/NPIX) * fc_w[o*48+k] + fc_b[o] )
// ghist layout [b][c][bin] == feat concat order.
__global__ __launch_bounds__(256) void fc_kernel(const unsigned int* __restrict__ ghist,
                                                 const float* __restrict__ fc_w,
                                                 const float* __restrict__ fc_b,
                                                 float* __restrict__ out) {
    const int tid = blockIdx.x * blockDim.x + threadIdx.x;  // 0..4095
    const int b = tid >> 6;
    const int o = tid & 63;
    const float inv_n = 1.0f / (float)NPIX;  // exact power-of-two
    float s = fc_b[o];
    #pragma unroll
    for (int k = 0; k < NCH * BINS; ++k) {
        s = fmaf((float)ghist[b * (NCH * BINS) + k] * inv_n, fc_w[o * (NCH * BINS) + k], s);
    }
    out[tid] = fmaxf(s, 0.0f);
}

extern "C" void kernel_launch(void* const* d_in, const int* in_sizes, int n_in,
                              void* d_out, int out_size, void* d_ws, size_t ws_size,
                              hipStream_t stream) {
    const float* x    = (const float*)d_in[0];
    const float* fc_w = (const float*)d_in[1];
    const float* fc_b = (const float*)d_in[2];
    float* out = (float*)d_out;
    unsigned int* ghist = (unsigned int*)d_ws;   // [192][16] uint counts

    hipMemsetAsync(ghist, 0, NB * NCH * BINS * sizeof(unsigned int), stream);
    hist_kernel<<<NB * NCH * BLOCKS_PER_PLANE, THREADS, 0, stream>>>(x, ghist);
    fc_kernel<<<(NB * OUT_DIM) / 256, 256, 0, stream>>>(ghist, fc_w, fc_b, out);
}

// Round 2
// 36.465 us; speedup vs baseline: 1.1474x; 1.1474x over previous
//
#include <hip/hip_runtime.h>

#define BINS 16
#define OUT_DIM 64
#define NB 64
#define NCH 3
#define NPIX (512 * 512)           // pixels per (b,c) plane
#define THREADS 256
#define BLOCKS_PER_PLANE 16
#define CHUNK_PIX (NPIX / BLOCKS_PER_PLANE)        // 16384 pixels per block
#define VEC_ITERS (CHUNK_PIX / 4 / THREADS)        // 16 float4 per thread
#define IN_DIM (NCH * BINS)                        // 48

// Kernel 1: per-(plane,chunk) partial 16-bin histogram.
// LDS histogram replicated 64x (one copy per lane): addr = bin*64 + lane ->
// bank = lane%32: only the free 2-way lane aliasing, zero same-address
// contention. Each block writes its 16 partial counts NON-atomically to its
// own ws slot: ws[(plane*BLOCKS_PER_PLANE + chunk)*BINS + bin].
__global__ __launch_bounds__(THREADS) void hist_kernel(const float* __restrict__ x,
                                                       unsigned int* __restrict__ partials) {
    __shared__ unsigned int lh[BINS * 64];
    for (int i = threadIdx.x; i < BINS * 64; i += THREADS) lh[i] = 0u;
    __syncthreads();

    const int lane = threadIdx.x & 63;
    const float4* __restrict__ src =
        (const float4*)(x + (size_t)blockIdx.x * CHUNK_PIX);

    #pragma unroll
    for (int it = 0; it < VEC_ITERS; ++it) {
        float4 v = src[it * THREADS + threadIdx.x];
        // x in [0,1): (int)(x*16.0f) == floor(x*16) exactly (mul by 2^4 exact).
        // min(15,.) guards an exact-1.0 input from an OOB LDS write.
        int i0 = min(BINS - 1, (int)(v.x * 16.0f));
        int i1 = min(BINS - 1, (int)(v.y * 16.0f));
        int i2 = min(BINS - 1, (int)(v.z * 16.0f));
        int i3 = min(BINS - 1, (int)(v.w * 16.0f));
        atomicAdd(&lh[i0 * 64 + lane], 1u);
        atomicAdd(&lh[i1 * 64 + lane], 1u);
        atomicAdd(&lh[i2 * 64 + lane], 1u);
        atomicAdd(&lh[i3 * 64 + lane], 1u);
    }
    __syncthreads();

    if (threadIdx.x < BINS) {
        unsigned int s = 0;
        #pragma unroll
        for (int k = 0; k < 64; ++k) s += lh[threadIdx.x * 64 + k];
        partials[blockIdx.x * BINS + threadIdx.x] = s;   // non-atomic store
    }
}

// Kernel 2: one block per batch b. Reduce 3ch x 16chunks x 16bins partials ->
// feat[48], then out[b][o] = relu(feat . fc_w[o] + fc_b[o]) for o in 0..63.
__global__ __launch_bounds__(256) void fc_kernel(const unsigned int* __restrict__ partials,
                                                 const float* __restrict__ fc_w,
                                                 const float* __restrict__ fc_b,
                                                 float* __restrict__ out) {
    __shared__ unsigned int tmp[NCH * BLOCKS_PER_PLANE * BINS];  // 768
    __shared__ float feat[IN_DIM];                               // 48
    const int b = blockIdx.x;
    const int tid = threadIdx.x;

    // load this batch's partials: layout [c][chunk][bin]
    const unsigned int* src = partials + (size_t)b * NCH * BLOCKS_PER_PLANE * BINS;
    #pragma unroll
    for (int i = tid; i < NCH * BLOCKS_PER_PLANE * BINS; i += 256) tmp[i] = src[i];
    __syncthreads();

    if (tid < IN_DIM) {                      // t = c*16 + bin
        const int c = tid >> 4, bin = tid & 15;
        unsigned int s = 0;
        #pragma unroll
        for (int ch = 0; ch < BLOCKS_PER_PLANE; ++ch)
            s += tmp[c * (BLOCKS_PER_PLANE * BINS) + ch * BINS + bin];
        feat[tid] = (float)s * (1.0f / (float)NPIX);   // exact pow2 divide
    }
    __syncthreads();

    if (tid < OUT_DIM) {
        float s = fc_b[tid];
        #pragma unroll
        for (int k = 0; k < IN_DIM; ++k)
            s = fmaf(feat[k], fc_w[tid * IN_DIM + k], s);
        out[b * OUT_DIM + tid] = fmaxf(s, 0.0f);
    }
}

extern "C" void kernel_launch(void* const* d_in, const int* in_sizes, int n_in,
                              void* d_out, int out_size, void* d_ws, size_t ws_size,
                              hipStream_t stream) {
    const float* x    = (const float*)d_in[0];
    const float* fc_w = (const float*)d_in[1];
    const float* fc_b = (const float*)d_in[2];
    float* out = (float*)d_out;
    unsigned int* partials = (unsigned int*)d_ws;  // [192 planes][16 chunks][16 bins]

    hist_kernel<<<NB * NCH * BLOCKS_PER_PLANE, THREADS, 0, stream>>>(x, partials);
    fc_kernel<<<NB, 256, 0, stream>>>(partials, fc_w, fc_b, out);
}